// Round 10
// baseline (300.544 us; speedup 1.0000x reference)
//
#include <hip/hip_runtime.h>

// GatedCrossModalAttention: B=16384, NM=5, D=256, H=8. FP32 I/O, bf16 internal.
// Attention collapses (Lq=Lk=1 => softmax==1):
//   branch_s(x) = x[:,mod_s] @ (Wo_s@Wv_s)^T + (Wo_s@bv_s+bo_s).
// K1: fuse weights -> WT bf16 in MFMA-fragment order, BF f32 [5][256]. ws 660 KB ONLY.
// Lessons (R2..R11):
//  - big ws corrupted inputs; ws stays tiny.
//  - MFMA-layout global I/O -> 2x traffic -> 2x slower (LDS park IS the converter).
//  - per-iteration re-staging thrashes caches; in-loop prefetch/coalescing = neutral
//    (loop was concurrency-starved) -> hoist ALL HBM to one prologue burst (R8: 72us).
//  - LDS slot-lifetime-reuse failed post-timing determinism. No overlap tricks.
//  - R10/R11: with LDS=40960 the compiler clamped VGPR to 64 and SPILLED the staging
//    regs (WRITE 16->198MB, k_main 147/156us). launch_bounds(256,4) and
//    amdgpu_waves_per_eu(4,4) both failed to raise the clamp.
//  - R6 PROVED __launch_bounds__(256,3) compiles this staging pattern at VGPR 84,
//    zero spill. Runtime residency is set by actual VGPR/LDS, not by the hint:
//    84 <= 128 VGPR allows 4 waves/EU; only R6's 43008B LDS blocked 4 blocks/CU.
// Round-12 (this): R11 kernel verbatim (passed 2x, absmax 0.047) + the R6
//   declaration: __launch_bounds__(256,3), no waves_per_eu. LDS stays 40960 B
//   exactly -> compiler ~90-110 VGPR no spill, runtime 4 blocks/CU, zero tail.

typedef __attribute__((ext_vector_type(8))) short short8;
typedef __attribute__((ext_vector_type(4))) float floatx4;

__device__ __forceinline__ float b2f(unsigned short h) {
    union { unsigned int u; float f; } v; v.u = ((unsigned int)h) << 16; return v.f;
}
__device__ __forceinline__ unsigned short f2b(float f) {
    union { unsigned int u; float f; } v; v.f = f;
    unsigned int u = v.u;
    return (unsigned short)((u + 0x7FFFu + ((u >> 16) & 1u)) >> 16);
}

// ---------------- K1: weight fusion ----------------
// grid (64, 5), block 256. Each block: 4 output rows (n = i0..i0+3) of one branch.
// Thread tid holds k=tid; computes WF[n][k] and scatters into WT fragment order:
//   WT[s][kk][w][ct][q4][l16][e] = WF[w*32+ct*16+l16][kk*32+q4*8+e]
__global__ __launch_bounds__(256) void k_fuse(
    const float* __restrict__ sWi, const float* __restrict__ sbi,
    const float* __restrict__ sWo, const float* __restrict__ sbo,
    const float* __restrict__ cWi, const float* __restrict__ cbi,
    const float* __restrict__ cWo, const float* __restrict__ cbo,
    unsigned short* __restrict__ WT, float* __restrict__ BF)
{
    int s = blockIdx.y;
    int i0 = blockIdx.x * 4;
    int tid = threadIdx.x;
    const float *Wo, *Wv, *bv, *bo;
    if (s == 0) { Wo = sWo; Wv = sWi + 512 * 256; bv = sbi + 512; bo = sbo; }
    else {
        int n = s - 1;
        Wo = cWo + n * 65536;
        Wv = cWi + n * 768 * 256 + 512 * 256;
        bv = cbi + n * 768 + 512;
        bo = cbo + n * 256;
    }
    __shared__ float wo[4 * 256];
    #pragma unroll
    for (int it = 0; it < 4; ++it) {
        int idx = tid + it * 256;
        wo[idx] = Wo[i0 * 256 + idx];
    }
    __syncthreads();
    float a0 = 0.f, a1 = 0.f, a2 = 0.f, a3 = 0.f;
    for (int k = 0; k < 256; ++k) {
        float wv = Wv[k * 256 + tid];
        a0 += wo[k] * wv;
        a1 += wo[256 + k] * wv;
        a2 += wo[512 + k] * wv;
        a3 += wo[768 + k] * wv;
    }
    // scatter into WT fragment order
    {
        unsigned short vals[4] = { f2b(a0), f2b(a1), f2b(a2), f2b(a3) };
        int kk = tid >> 5, q4k = (tid >> 3) & 3, e = tid & 7;
        #pragma unroll
        for (int r = 0; r < 4; ++r) {
            int n = i0 + r;
            int w = n >> 5, ct = (n >> 4) & 1, l16n = n & 15;
            size_t idx = (((((((size_t)s * 8 + kk) * 8 + w) * 2 + ct) * 4 + q4k) * 16 + l16n) * 8) + e;
            WT[idx] = vals[r];
        }
    }
    // bias: one wave per output row (parallel), lane l covers k=4l..4l+3
    {
        int wv_ = tid >> 6, ln = tid & 63;
        float p = 0.f;
        #pragma unroll
        for (int u = 0; u < 4; ++u) {
            int k = ln * 4 + u;
            p += wo[wv_ * 256 + k] * bv[k];
        }
        #pragma unroll
        for (int o = 32; o > 0; o >>= 1) p += __shfl_xor(p, o, 64);
        if (ln == 0) BF[s * 256 + i0 + wv_] = p + bo[i0 + wv_];
    }
}

// ---------------- K2: fused GEMM + epilogue ----------------
__device__ __forceinline__ float wred(float v) {
    #pragma unroll
    for (int o = 32; o > 0; o >>= 1) v += __shfl_xor(v, o, 64);
    return v;
}

// T2 XOR swizzle, SHORT units: flips byte bits 4..6 by row&7. Keeps 8B/16B alignment.
#define SWZ(r, c) ((c) ^ (((r) & 7) << 3))

// grid 1024, block 256 (4 waves). Block: rows [b0, b0+16). Wave w: GEMM cols
// [w*64, w*64+64) (ct=0..3), epilogue rows [w*4, w*4+4), lane j = lane*4.
// LDS: 5 slots x 16 rows x 256 shorts (40960 B exactly) -> 4 blocks/CU by LDS.
// launch_bounds(256,3): the declaration that compiled this staging at VGPR 84,
// no spill (R6). Runtime schedules 4 blocks/CU as long as VGPR <= 128.
__global__ __launch_bounds__(256, 3) void k_main(
    const float* __restrict__ x, const unsigned short* __restrict__ WT,
    const float* __restrict__ BF,
    const float* __restrict__ cln_g, const float* __restrict__ cln_b,
    const float* __restrict__ gln_g, const float* __restrict__ gln_b,
    const float* __restrict__ gW, const float* __restrict__ gb,
    const float* __restrict__ fln_g, const float* __restrict__ fln_b,
    const int* __restrict__ midx, float* __restrict__ out)
{
    __shared__ __align__(16) unsigned short Axl[5][16 * 256];  // 40,960 B exactly

    const int m = midx[0];
    const int b0 = blockIdx.x * 16;
    const int tid = threadIdx.x;
    const int wave = tid >> 6, lane = tid & 63;
    const int l16 = lane & 15, q4 = lane >> 4;
    const int j = lane * 4;

    // q rows (fp32, registers, for residuals): 4 rows per wave
    float qv[4][4];
    #pragma unroll
    for (int rr = 0; rr < 4; ++rr) {
        int r = wave * 4 + rr;
        float4 u = *(const float4*)(x + ((size_t)(b0 + r) * 5 + m) * 256 + j);
        qv[rr][0] = u.x; qv[rr][1] = u.y; qv[rr][2] = u.z; qv[rr][3] = u.w;
    }
    float4 glg = *(const float4*)(gln_g + j);
    float4 glb = *(const float4*)(gln_b + j);

    // ---- phase A: issue tiles 0..2 (latency hides under the gates compute) ----
    float4 srA[3][4];
    #pragma unroll
    for (int mi = 0; mi < 3; ++mi) {
        int mod = (mi == 0) ? m : ((mi - 1 < m) ? mi - 1 : mi);
        #pragma unroll
        for (int it = 0; it < 4; ++it) {
            int c = tid + it * 256;             // 16 rows x 64 float4
            srA[mi][it] = *(const float4*)(x + ((size_t)(b0 + (c >> 6)) * 5 + mod) * 256 + ((c & 63) << 2));
        }
    }

    // ---- gates, kept in REGISTERS (each wave needs only its own 4 rows) ----
    float gt[4][5];
    #pragma unroll
    for (int rr = 0; rr < 4; ++rr) {
        float s1 = wred(qv[rr][0] + qv[rr][1] + qv[rr][2] + qv[rr][3]);
        float s2 = wred(qv[rr][0]*qv[rr][0] + qv[rr][1]*qv[rr][1] +
                        qv[rr][2]*qv[rr][2] + qv[rr][3]*qv[rr][3]);
        float mn = s1 * (1.f / 256.f);
        float vr = s2 * (1.f / 256.f) - mn * mn;
        float rs = rsqrtf(vr + 1e-5f);
        float qln[4];
        qln[0] = (qv[rr][0] - mn) * rs * glg.x + glb.x;
        qln[1] = (qv[rr][1] - mn) * rs * glg.y + glb.y;
        qln[2] = (qv[rr][2] - mn) * rs * glg.z + glb.z;
        qln[3] = (qv[rr][3] - mn) * rs * glg.w + glb.w;
        float g[5];
        #pragma unroll
        for (int n = 0; n < 5; ++n) {
            float4 w4 = *(const float4*)(gW + n * 256 + j);
            float p = qln[0] * w4.x + qln[1] * w4.y + qln[2] * w4.z + qln[3] * w4.w;
            g[n] = wred(p) + gb[n];
        }
        float mx = g[0];
        #pragma unroll
        for (int n = 1; n < 5; ++n) mx = fmaxf(mx, g[n]);
        float es = 0.f;
        #pragma unroll
        for (int n = 0; n < 5; ++n) { g[n] = __expf(g[n] - mx); es += g[n]; }
        float inv = 1.f / es;
        #pragma unroll
        for (int n = 0; n < 5; ++n) gt[rr][n] = g[n] * inv;
    }

    // ---- write tiles 0..2 to LDS (their loads have drained under the gates) ----
    #pragma unroll
    for (int mi = 0; mi < 3; ++mi) {
        #pragma unroll
        for (int it = 0; it < 4; ++it) {
            int c = tid + it * 256;
            int row = c >> 6;
            int cs = (c & 63) << 2;
            float4 v = srA[mi][it];
            uint2 p;
            p.x = (unsigned int)f2b(v.x) | ((unsigned int)f2b(v.y) << 16);
            p.y = (unsigned int)f2b(v.z) | ((unsigned int)f2b(v.w) << 16);
            *(uint2*)(&Axl[mi][row * 256 + SWZ(row, cs)]) = p;
        }
    }

    // ---- phase B: issue + write tiles 3..4 (peak staging regs only 8 float4) ----
    float4 srB[2][4];
    #pragma unroll
    for (int mi = 0; mi < 2; ++mi) {
        int mod = (mi + 2 < m) ? mi + 2 : mi + 3;   // modal of branch mi+3
        #pragma unroll
        for (int it = 0; it < 4; ++it) {
            int c = tid + it * 256;
            srB[mi][it] = *(const float4*)(x + ((size_t)(b0 + (c >> 6)) * 5 + mod) * 256 + ((c & 63) << 2));
        }
    }
    #pragma unroll
    for (int mi = 0; mi < 2; ++mi) {
        #pragma unroll
        for (int it = 0; it < 4; ++it) {
            int c = tid + it * 256;
            int row = c >> 6;
            int cs = (c & 63) << 2;
            float4 v = srB[mi][it];
            uint2 p;
            p.x = (unsigned int)f2b(v.x) | ((unsigned int)f2b(v.y) << 16);
            p.y = (unsigned int)f2b(v.z) | ((unsigned int)f2b(v.w) << 16);
            *(uint2*)(&Axl[mi + 3][row * 256 + SWZ(row, cs)]) = p;
        }
    }
    __syncthreads();  // all tiles ready; NO HBM x-reads from here on

    float comb[4][4];
    #pragma unroll
    for (int rr = 0; rr < 4; ++rr)
        #pragma unroll
        for (int i = 0; i < 4; ++i) comb[rr][i] = 0.f;

    #pragma unroll
    for (int s = 0; s < 5; ++s) {
        float4 bfv = *(const float4*)(BF + s * 256 + j);
        float4 cg, cb;
        if (s > 0) {
            cg = *(const float4*)(cln_g + (s - 1) * 256 + j);
            cb = *(const float4*)(cln_b + (s - 1) * 256 + j);
        }

        // GEMM: 16x256 = A(16x256) @ WF_s^T ; wave covers 64 cols (ct=0..3).
        floatx4 acc[4];
        #pragma unroll
        for (int ct = 0; ct < 4; ++ct) acc[ct] = (floatx4){0.f, 0.f, 0.f, 0.f};
        const unsigned short* wT = WT + (size_t)s * 65536;
        #pragma unroll
        for (int h = 0; h < 8; ++h) {
            short8 bb[4];
            #pragma unroll
            for (int ct = 0; ct < 4; ++ct) {
                int wp = wave * 2 + (ct >> 1), ctp = ct & 1;
                bb[ct] = *(const short8*)(
                    wT + (((((size_t)h * 8 + wp) * 2 + ctp) * 4 + q4) * 16 + l16) * 8);
            }
            int k = h * 32 + q4 * 8;
            short8 a = *(const short8*)(&Axl[s][l16 * 256 + SWZ(l16, k)]);
            #pragma unroll
            for (int ct = 0; ct < 4; ++ct)
                acc[ct] = __builtin_amdgcn_mfma_f32_16x16x32_bf16(a, bb[ct], acc[ct], 0, 0, 0);
        }
        __syncthreads();  // B_a: all waves done READING Axl[s]

        // park Y in place over Axl[s] (MFMA C-layout -> row-major, swizzled)
        #pragma unroll
        for (int i = 0; i < 4; ++i) {
            int r = q4 * 4 + i;
            #pragma unroll
            for (int ct = 0; ct < 4; ++ct)
                Axl[s][r * 256 + SWZ(r, wave * 64 + ct * 16 + l16)] = f2b(acc[ct][i]);
        }
        __syncthreads();  // B1: park visible

        // epilogue partial: comb += g_s * (s==0 ? y : LN(q+y))
        if (s == 0) {
            #pragma unroll
            for (int rr = 0; rr < 4; ++rr) {
                int r = wave * 4 + rr;
                uint2 u = *(const uint2*)(&Axl[s][r * 256 + SWZ(r, j)]);
                float y0 = b2f(u.x & 0xffff) + bfv.x, y1 = b2f(u.x >> 16) + bfv.y;
                float y2 = b2f(u.y & 0xffff) + bfv.z, y3 = b2f(u.y >> 16) + bfv.w;
                float g0 = gt[rr][0];
                comb[rr][0] += g0 * y0; comb[rr][1] += g0 * y1;
                comb[rr][2] += g0 * y2; comb[rr][3] += g0 * y3;
            }
        } else {
            #pragma unroll
            for (int rr = 0; rr < 4; ++rr) {
                int r = wave * 4 + rr;
                uint2 u = *(const uint2*)(&Axl[s][r * 256 + SWZ(r, j)]);
                float t0 = qv[rr][0] + b2f(u.x & 0xffff) + bfv.x;
                float t1 = qv[rr][1] + b2f(u.x >> 16)    + bfv.y;
                float t2 = qv[rr][2] + b2f(u.y & 0xffff) + bfv.z;
                float t3 = qv[rr][3] + b2f(u.y >> 16)    + bfv.w;
                float s1 = wred(t0 + t1 + t2 + t3);
                float s2 = wred(t0*t0 + t1*t1 + t2*t2 + t3*t3);
                float mn = s1 * (1.f / 256.f);
                float vr = s2 * (1.f / 256.f) - mn * mn;
                float rs = rsqrtf(vr + 1e-5f);
                float gs = gt[rr][s];
                comb[rr][0] += gs * ((t0 - mn) * rs * cg.x + cb.x);
                comb[rr][1] += gs * ((t1 - mn) * rs * cg.y + cb.y);
                comb[rr][2] += gs * ((t2 - mn) * rs * cg.z + cb.z);
                comb[rr][3] += gs * ((t3 - mn) * rs * cg.w + cb.w);
            }
        }
        // no barrier at loop end: next iteration's GEMM touches only Axl[s+1];
        // this slot is never written again.
    }

    // final LN and store (float4-coalesced)
    float4 fg = *(const float4*)(fln_g + j);
    float4 fb = *(const float4*)(fln_b + j);
    #pragma unroll
    for (int rr = 0; rr < 4; ++rr) {
        int r = wave * 4 + rr;
        float t0 = qv[rr][0] + comb[rr][0], t1 = qv[rr][1] + comb[rr][1];
        float t2 = qv[rr][2] + comb[rr][2], t3 = qv[rr][3] + comb[rr][3];
        float s1 = wred(t0 + t1 + t2 + t3);
        float s2 = wred(t0*t0 + t1*t1 + t2*t2 + t3*t3);
        float mn = s1 * (1.f / 256.f);
        float vr = s2 * (1.f / 256.f) - mn * mn;
        float rs = rsqrtf(vr + 1e-5f);
        float4 ov;
        ov.x = (t0 - mn) * rs * fg.x + fb.x;
        ov.y = (t1 - mn) * rs * fg.y + fb.y;
        ov.z = (t2 - mn) * rs * fg.z + fb.z;
        ov.w = (t3 - mn) * rs * fg.w + fb.w;
        *(float4*)(out + (size_t)(b0 + r) * 256 + j) = ov;
    }
}

extern "C" void kernel_launch(void* const* d_in, const int* in_sizes, int n_in,
                              void* d_out, int out_size, void* d_ws, size_t ws_size,
                              hipStream_t stream) {
    const float* x    = (const float*)d_in[0];
    const float* sWi  = (const float*)d_in[1];
    const float* sbi  = (const float*)d_in[2];
    const float* sWo  = (const float*)d_in[3];
    const float* sbo  = (const float*)d_in[4];
    const float* cWi  = (const float*)d_in[5];
    const float* cbi  = (const float*)d_in[6];
    const float* cWo  = (const float*)d_in[7];
    const float* cbo  = (const float*)d_in[8];
    const float* clng = (const float*)d_in[9];
    const float* clnb = (const float*)d_in[10];
    const float* glng = (const float*)d_in[11];
    const float* glnb = (const float*)d_in[12];
    const float* gW   = (const float*)d_in[13];
    const float* gb   = (const float*)d_in[14];
    const float* flng = (const float*)d_in[15];
    const float* flnb = (const float*)d_in[16];
    const int* midx   = (const int*)d_in[17];
    float* out        = (float*)d_out;

    char* ws = (char*)d_ws;
    unsigned short* WT = (unsigned short*)ws;         // 5*256*256*2 = 655360 B (fragment order)
    float* BF          = (float*)(ws + 655360);       // 5*256*4 = 5120 B  (total 660480 B)

    k_fuse<<<dim3(64, 5), 256, 0, stream>>>(sWi, sbi, sWo, sbo, cWi, cbi, cWo, cbo, WT, BF);
    k_main<<<1024, 256, 0, stream>>>(x, WT, BF, clng, clnb, glng, glnb, gW, gb, flng, flnb, midx, out);
}

// Round 11
// 279.950 us; speedup vs baseline: 1.0736x; 1.0736x over previous
//
#include <hip/hip_runtime.h>

// GatedCrossModalAttention: B=16384, NM=5, D=256, H=8. FP32 I/O, bf16 internal.
// Attention collapses (Lq=Lk=1 => softmax==1):
//   branch_s(x) = x[:,mod_s] @ (Wo_s@Wv_s)^T + (Wo_s@bv_s+bo_s).
// K1: fuse weights -> WT bf16 in MFMA-fragment order, BF f32 [5][256]. ws 660 KB ONLY.
// Lessons (R2..R12):
//  - big ws corrupted inputs; MFMA-layout global I/O -> 2x traffic (LDS park IS the
//    layout converter); per-iteration re-staging thrashes caches; in-loop prefetch
//    and WT coalescing neutral (loop concurrency-starved) -> hoist ALL HBM to one
//    prologue burst (R6: 72.4us, VGPR 84, WRITE 16.4MB, CLEAN).
//  - LDS slot-lifetime-reuse failed post-timing determinism. No overlap tricks.
//  - 40960B variants (R8/R11/R12) all show phantom traffic (WRITE 121-198MB =
//    scratch): R8 launch_bounds(256,4) clamped VGPR to 64 + spill; R12 (256,3)
//    restored VGPR 84 but traffic persisted -> remaining suspects: gt[4][5] gate
//    array live across whole kernel (+20 regs vs R6's gLDS) and two-phase staging
//    live-ranges. R6 with same staging volume + gates-in-LDS compiled clean.
// Round-13 (this): R6-verbatim body with exactly two LDS-budget edits:
//   (a) SWZ xor-swizzle replaces the ASTR-264 pad (same measured bank conflicts),
//   (b) gates distributed 5 regs/lane (lane&3 keeps its row; epilogue broadcasts
//       via __shfl(gk[s], rr, 4)) instead of 512B gLDS. Single-phase staging,
//   __launch_bounds__(256,3). LDS = 40960B exactly -> 4 blocks/CU, zero tail.

typedef __attribute__((ext_vector_type(8))) short short8;
typedef __attribute__((ext_vector_type(4))) float floatx4;

__device__ __forceinline__ float b2f(unsigned short h) {
    union { unsigned int u; float f; } v; v.u = ((unsigned int)h) << 16; return v.f;
}
__device__ __forceinline__ unsigned short f2b(float f) {
    union { unsigned int u; float f; } v; v.f = f;
    unsigned int u = v.u;
    return (unsigned short)((u + 0x7FFFu + ((u >> 16) & 1u)) >> 16);
}

// ---------------- K1: weight fusion ----------------
// grid (64, 5), block 256. Each block: 4 output rows (n = i0..i0+3) of one branch.
// Thread tid holds k=tid; computes WF[n][k] and scatters into WT fragment order:
//   WT[s][kk][w][ct][q4][l16][e] = WF[w*32+ct*16+l16][kk*32+q4*8+e]
__global__ __launch_bounds__(256) void k_fuse(
    const float* __restrict__ sWi, const float* __restrict__ sbi,
    const float* __restrict__ sWo, const float* __restrict__ sbo,
    const float* __restrict__ cWi, const float* __restrict__ cbi,
    const float* __restrict__ cWo, const float* __restrict__ cbo,
    unsigned short* __restrict__ WT, float* __restrict__ BF)
{
    int s = blockIdx.y;
    int i0 = blockIdx.x * 4;
    int tid = threadIdx.x;
    const float *Wo, *Wv, *bv, *bo;
    if (s == 0) { Wo = sWo; Wv = sWi + 512 * 256; bv = sbi + 512; bo = sbo; }
    else {
        int n = s - 1;
        Wo = cWo + n * 65536;
        Wv = cWi + n * 768 * 256 + 512 * 256;
        bv = cbi + n * 768 + 512;
        bo = cbo + n * 256;
    }
    __shared__ float wo[4 * 256];
    #pragma unroll
    for (int it = 0; it < 4; ++it) {
        int idx = tid + it * 256;
        wo[idx] = Wo[i0 * 256 + idx];
    }
    __syncthreads();
    float a0 = 0.f, a1 = 0.f, a2 = 0.f, a3 = 0.f;
    for (int k = 0; k < 256; ++k) {
        float wv = Wv[k * 256 + tid];
        a0 += wo[k] * wv;
        a1 += wo[256 + k] * wv;
        a2 += wo[512 + k] * wv;
        a3 += wo[768 + k] * wv;
    }
    // scatter into WT fragment order
    {
        unsigned short vals[4] = { f2b(a0), f2b(a1), f2b(a2), f2b(a3) };
        int kk = tid >> 5, q4k = (tid >> 3) & 3, e = tid & 7;
        #pragma unroll
        for (int r = 0; r < 4; ++r) {
            int n = i0 + r;
            int w = n >> 5, ct = (n >> 4) & 1, l16n = n & 15;
            size_t idx = (((((((size_t)s * 8 + kk) * 8 + w) * 2 + ct) * 4 + q4k) * 16 + l16n) * 8) + e;
            WT[idx] = vals[r];
        }
    }
    // bias: one wave per output row (parallel), lane l covers k=4l..4l+3
    {
        int wv_ = tid >> 6, ln = tid & 63;
        float p = 0.f;
        #pragma unroll
        for (int u = 0; u < 4; ++u) {
            int k = ln * 4 + u;
            p += wo[wv_ * 256 + k] * bv[k];
        }
        #pragma unroll
        for (int o = 32; o > 0; o >>= 1) p += __shfl_xor(p, o, 64);
        if (ln == 0) BF[s * 256 + i0 + wv_] = p + bo[i0 + wv_];
    }
}

// ---------------- K2: fused GEMM + epilogue ----------------
__device__ __forceinline__ float wred(float v) {
    #pragma unroll
    for (int o = 32; o > 0; o >>= 1) v += __shfl_xor(v, o, 64);
    return v;
}

// T2 XOR swizzle, SHORT units: flips short-index bits 3..5 by row&7.
// XOR operand is a multiple of 8 shorts -> preserves 8B/16B access alignment.
#define SWZ(r, c) ((c) ^ (((r) & 7) << 3))

// grid 1024, block 256 (4 waves). Block: rows [b0, b0+16). Wave w: GEMM cols
// [w*64, w*64+64) (ct=0..3), epilogue rows [w*4, w*4+4), lane j = lane*4.
// LDS: 5 slots x 16 rows x 256 shorts = 40960 B exactly -> 4 blocks/CU by LDS.
// launch_bounds(256,3): the R6 declaration (VGPR 84, no spill).
__global__ __launch_bounds__(256, 3) void k_main(
    const float* __restrict__ x, const unsigned short* __restrict__ WT,
    const float* __restrict__ BF,
    const float* __restrict__ cln_g, const float* __restrict__ cln_b,
    const float* __restrict__ gln_g, const float* __restrict__ gln_b,
    const float* __restrict__ gW, const float* __restrict__ gb,
    const float* __restrict__ fln_g, const float* __restrict__ fln_b,
    const int* __restrict__ midx, float* __restrict__ out)
{
    __shared__ __align__(16) unsigned short Axl[5][16 * 256];  // 40,960 B exactly

    const int m = midx[0];
    const int b0 = blockIdx.x * 16;
    const int tid = threadIdx.x;
    const int wave = tid >> 6, lane = tid & 63;
    const int l16 = lane & 15, q4 = lane >> 4;
    const int j = lane * 4;

    // ---- prologue: issue ALL modal stage loads (one burst; R6's exact pattern) ----
    float4 sreg[5][4];
    #pragma unroll
    for (int mi = 0; mi < 5; ++mi) {
        int mod = (mi == 0) ? m : ((mi - 1 < m) ? mi - 1 : mi);
        #pragma unroll
        for (int it = 0; it < 4; ++it) {
            int c = tid + it * 256;             // 16 rows x 64 float4
            sreg[mi][it] = *(const float4*)(x + ((size_t)(b0 + (c >> 6)) * 5 + mod) * 256 + ((c & 63) << 2));
        }
    }

    // q rows (fp32, registers, for residuals): 4 rows per wave
    float qv[4][4];
    #pragma unroll
    for (int rr = 0; rr < 4; ++rr) {
        int r = wave * 4 + rr;
        float4 u = *(const float4*)(x + ((size_t)(b0 + r) * 5 + m) * 256 + j);
        qv[rr][0] = u.x; qv[rr][1] = u.y; qv[rr][2] = u.z; qv[rr][3] = u.w;
    }
    float4 glg = *(const float4*)(gln_g + j);
    float4 glb = *(const float4*)(gln_b + j);

    // ---- gates (overlap the stage-load latency), DISTRIBUTED: lane (lane&3)==rr
    //      keeps the 5 gates of row wave*4+rr (5 long-lived regs/lane, not 20) ----
    float gk[5] = {0.f, 0.f, 0.f, 0.f, 0.f};
    #pragma unroll
    for (int rr = 0; rr < 4; ++rr) {
        float s1 = wred(qv[rr][0] + qv[rr][1] + qv[rr][2] + qv[rr][3]);
        float s2 = wred(qv[rr][0]*qv[rr][0] + qv[rr][1]*qv[rr][1] +
                        qv[rr][2]*qv[rr][2] + qv[rr][3]*qv[rr][3]);
        float mn = s1 * (1.f / 256.f);
        float vr = s2 * (1.f / 256.f) - mn * mn;
        float rs = rsqrtf(vr + 1e-5f);
        float qln[4];
        qln[0] = (qv[rr][0] - mn) * rs * glg.x + glb.x;
        qln[1] = (qv[rr][1] - mn) * rs * glg.y + glb.y;
        qln[2] = (qv[rr][2] - mn) * rs * glg.z + glb.z;
        qln[3] = (qv[rr][3] - mn) * rs * glg.w + glb.w;
        float g[5];
        #pragma unroll
        for (int n = 0; n < 5; ++n) {
            float4 w4 = *(const float4*)(gW + n * 256 + j);
            float p = qln[0] * w4.x + qln[1] * w4.y + qln[2] * w4.z + qln[3] * w4.w;
            g[n] = wred(p) + gb[n];
        }
        float mx = g[0];
        #pragma unroll
        for (int n = 1; n < 5; ++n) mx = fmaxf(mx, g[n]);
        float es = 0.f;
        #pragma unroll
        for (int n = 0; n < 5; ++n) { g[n] = __expf(g[n] - mx); es += g[n]; }
        float inv = 1.f / es;
        if ((lane & 3) == rr) {
            #pragma unroll
            for (int n = 0; n < 5; ++n) gk[n] = g[n] * inv;
        }
    }

    // ---- write all 5 staged tiles to LDS (bf16, swizzled) ----
    #pragma unroll
    for (int mi = 0; mi < 5; ++mi) {
        #pragma unroll
        for (int it = 0; it < 4; ++it) {
            int c = tid + it * 256;
            int row = c >> 6;
            int cs = (c & 63) << 2;
            float4 v = sreg[mi][it];
            uint2 p;
            p.x = (unsigned int)f2b(v.x) | ((unsigned int)f2b(v.y) << 16);
            p.y = (unsigned int)f2b(v.z) | ((unsigned int)f2b(v.w) << 16);
            *(uint2*)(&Axl[mi][row * 256 + SWZ(row, cs)]) = p;
        }
    }
    __syncthreads();  // all tiles ready; NO HBM x-reads from here on

    float comb[4][4];
    #pragma unroll
    for (int rr = 0; rr < 4; ++rr)
        #pragma unroll
        for (int i = 0; i < 4; ++i) comb[rr][i] = 0.f;

    #pragma unroll
    for (int s = 0; s < 5; ++s) {
        float4 bfv = *(const float4*)(BF + s * 256 + j);
        float4 cg, cb;
        if (s > 0) {
            cg = *(const float4*)(cln_g + (s - 1) * 256 + j);
            cb = *(const float4*)(cln_b + (s - 1) * 256 + j);
        }
        // broadcast this branch's gates for the wave's 4 rows (from keeper lanes)
        float gsr[4];
        #pragma unroll
        for (int rr = 0; rr < 4; ++rr) gsr[rr] = __shfl(gk[s], rr, 4);

        // GEMM: 16x256 = A(16x256) @ WF_s^T ; wave covers 64 cols (ct=0..3).
        floatx4 acc[4];
        #pragma unroll
        for (int ct = 0; ct < 4; ++ct) acc[ct] = (floatx4){0.f, 0.f, 0.f, 0.f};
        const unsigned short* wT = WT + (size_t)s * 65536;
        #pragma unroll
        for (int h = 0; h < 8; ++h) {
            short8 bb[4];
            #pragma unroll
            for (int ct = 0; ct < 4; ++ct) {
                int wp = wave * 2 + (ct >> 1), ctp = ct & 1;
                bb[ct] = *(const short8*)(
                    wT + (((((size_t)h * 8 + wp) * 2 + ctp) * 4 + q4) * 16 + l16) * 8);
            }
            int k = h * 32 + q4 * 8;
            short8 a = *(const short8*)(&Axl[s][l16 * 256 + SWZ(l16, k)]);
            #pragma unroll
            for (int ct = 0; ct < 4; ++ct)
                acc[ct] = __builtin_amdgcn_mfma_f32_16x16x32_bf16(a, bb[ct], acc[ct], 0, 0, 0);
        }
        __syncthreads();  // B_a: all waves done READING Axl[s]

        // park Y in place over Axl[s] (MFMA C-layout -> row-major, swizzled)
        #pragma unroll
        for (int i = 0; i < 4; ++i) {
            int r = q4 * 4 + i;
            #pragma unroll
            for (int ct = 0; ct < 4; ++ct)
                Axl[s][r * 256 + SWZ(r, wave * 64 + ct * 16 + l16)] = f2b(acc[ct][i]);
        }
        __syncthreads();  // B1: park visible

        // epilogue partial: comb += g_s * (s==0 ? y : LN(q+y))
        if (s == 0) {
            #pragma unroll
            for (int rr = 0; rr < 4; ++rr) {
                int r = wave * 4 + rr;
                uint2 u = *(const uint2*)(&Axl[s][r * 256 + SWZ(r, j)]);
                float y0 = b2f(u.x & 0xffff) + bfv.x, y1 = b2f(u.x >> 16) + bfv.y;
                float y2 = b2f(u.y & 0xffff) + bfv.z, y3 = b2f(u.y >> 16) + bfv.w;
                float g0 = gsr[rr];
                comb[rr][0] += g0 * y0; comb[rr][1] += g0 * y1;
                comb[rr][2] += g0 * y2; comb[rr][3] += g0 * y3;
            }
        } else {
            #pragma unroll
            for (int rr = 0; rr < 4; ++rr) {
                int r = wave * 4 + rr;
                uint2 u = *(const uint2*)(&Axl[s][r * 256 + SWZ(r, j)]);
                float t0 = qv[rr][0] + b2f(u.x & 0xffff) + bfv.x;
                float t1 = qv[rr][1] + b2f(u.x >> 16)    + bfv.y;
                float t2 = qv[rr][2] + b2f(u.y & 0xffff) + bfv.z;
                float t3 = qv[rr][3] + b2f(u.y >> 16)    + bfv.w;
                float s1 = wred(t0 + t1 + t2 + t3);
                float s2 = wred(t0*t0 + t1*t1 + t2*t2 + t3*t3);
                float mn = s1 * (1.f / 256.f);
                float vr = s2 * (1.f / 256.f) - mn * mn;
                float rs = rsqrtf(vr + 1e-5f);
                float gs = gsr[rr];
                comb[rr][0] += gs * ((t0 - mn) * rs * cg.x + cb.x);
                comb[rr][1] += gs * ((t1 - mn) * rs * cg.y + cb.y);
                comb[rr][2] += gs * ((t2 - mn) * rs * cg.z + cb.z);
                comb[rr][3] += gs * ((t3 - mn) * rs * cg.w + cb.w);
            }
        }
        // no barrier at loop end: next iteration's GEMM touches only Axl[s+1];
        // this slot is never written again.
    }

    // final LN and store (float4-coalesced)
    float4 fg = *(const float4*)(fln_g + j);
    float4 fb = *(const float4*)(fln_b + j);
    #pragma unroll
    for (int rr = 0; rr < 4; ++rr) {
        int r = wave * 4 + rr;
        float t0 = qv[rr][0] + comb[rr][0], t1 = qv[rr][1] + comb[rr][1];
        float t2 = qv[rr][2] + comb[rr][2], t3 = qv[rr][3] + comb[rr][3];
        float s1 = wred(t0 + t1 + t2 + t3);
        float s2 = wred(t0*t0 + t1*t1 + t2*t2 + t3*t3);
        float mn = s1 * (1.f / 256.f);
        float vr = s2 * (1.f / 256.f) - mn * mn;
        float rs = rsqrtf(vr + 1e-5f);
        float4 ov;
        ov.x = (t0 - mn) * rs * fg.x + fb.x;
        ov.y = (t1 - mn) * rs * fg.y + fb.y;
        ov.z = (t2 - mn) * rs * fg.z + fb.z;
        ov.w = (t3 - mn) * rs * fg.w + fb.w;
        *(float4*)(out + (size_t)(b0 + r) * 256 + j) = ov;
    }
}

extern "C" void kernel_launch(void* const* d_in, const int* in_sizes, int n_in,
                              void* d_out, int out_size, void* d_ws, size_t ws_size,
                              hipStream_t stream) {
    const float* x    = (const float*)d_in[0];
    const float* sWi  = (const float*)d_in[1];
    const float* sbi  = (const float*)d_in[2];
    const float* sWo  = (const float*)d_in[3];
    const float* sbo  = (const float*)d_in[4];
    const float* cWi  = (const float*)d_in[5];
    const float* cbi  = (const float*)d_in[6];
    const float* cWo  = (const float*)d_in[7];
    const float* cbo  = (const float*)d_in[8];
    const float* clng = (const float*)d_in[9];
    const float* clnb = (const float*)d_in[10];
    const float* glng = (const float*)d_in[11];
    const float* glnb = (const float*)d_in[12];
    const float* gW   = (const float*)d_in[13];
    const float* gb   = (const float*)d_in[14];
    const float* flng = (const float*)d_in[15];
    const float* flnb = (const float*)d_in[16];
    const int* midx   = (const int*)d_in[17];
    float* out        = (float*)d_out;

    char* ws = (char*)d_ws;
    unsigned short* WT = (unsigned short*)ws;         // 5*256*256*2 = 655360 B (fragment order)
    float* BF          = (float*)(ws + 655360);       // 5*256*4 = 5120 B  (total 660480 B)

    k_fuse<<<dim3(64, 5), 256, 0, stream>>>(sWi, sbi, sWo, sbo, cWi, cbi, cWo, cbo, WT, BF);
    k_main<<<1024, 256, 0, stream>>>(x, WT, BF, clng, clnb, glng, glnb, gW, gb, flng, flnb, midx, out);
}

// Round 12
// 272.982 us; speedup vs baseline: 1.1010x; 1.0255x over previous
//
#include <hip/hip_runtime.h>

// GatedCrossModalAttention: B=16384, NM=5, D=256, H=8. FP32 I/O, bf16 internal.
// Attention collapses (Lq=Lk=1 => softmax==1):
//   branch_s(x) = x[:,mod_s] @ (Wo_s@Wv_s)^T + (Wo_s@bv_s+bo_s).
// K1: fuse weights -> WT bf16 in MFMA-fragment order, BF f32 [5][256]. ws 660 KB ONLY.
// Lessons (R2..R13):
//  - big ws corrupted inputs; MFMA-layout global I/O -> 2x traffic (LDS park IS the
//    layout converter); per-iteration re-staging thrashes caches; in-loop prefetch
//    and WT coalescing neutral -> hoist ALL HBM to one prologue burst (R6: 72.4us,
//    VGPR 84, WRITE 16.4MB, CLEAN at 43008B LDS / 3 blocks/CU).
//  - R7-style deferred A-write into a consumed slot failed post-timing determinism.
//    In-place Y-park over the slot's own A (write-after-read across barriers) is
//    fine and has passed every round.
//  - 5-slot 40960B variants (R8/R10/R11 kernels) ALL spill staging to scratch
//    regardless of hints: WRITE 198/121/84 MB vs 16.4 ideal. launch_bounds(256,4),
//    waves_per_eu(4,4), two-phase staging, gates-in-regs: none fixed it. The
//    compiler pipelines 20-float4 staging cleanly ONLY in the R6 configuration.
// Round-14 (this): make the staging set structurally small instead of fighting
//   regalloc: branch 0's A-tile (modal m, L1/L2-hot) is read DIRECTLY from global
//   as MFMA fragments (fp32->bf16 in-loop), so only branches 1-4 stage in LDS.
//   4 slots * ASTR 264 (R6's pad, no SWZ) + gLDS = 34304 B -> 4 blocks/CU.
//   Branch order [1,2,3,4,0]; branch 0 parks into slot 0 (its Y(1) was consumed
//   4 barrier-phases earlier). Staging = 16 float4. Declaration = R6's (256,3).

typedef __attribute__((ext_vector_type(8))) short short8;
typedef __attribute__((ext_vector_type(4))) float floatx4;

__device__ __forceinline__ float b2f(unsigned short h) {
    union { unsigned int u; float f; } v; v.u = ((unsigned int)h) << 16; return v.f;
}
__device__ __forceinline__ unsigned short f2b(float f) {
    union { unsigned int u; float f; } v; v.f = f;
    unsigned int u = v.u;
    return (unsigned short)((u + 0x7FFFu + ((u >> 16) & 1u)) >> 16);
}

// ---------------- K1: weight fusion ----------------
// grid (64, 5), block 256. Each block: 4 output rows (n = i0..i0+3) of one branch.
// Thread tid holds k=tid; computes WF[n][k] and scatters into WT fragment order:
//   WT[s][kk][w][ct][q4][l16][e] = WF[w*32+ct*16+l16][kk*32+q4*8+e]
__global__ __launch_bounds__(256) void k_fuse(
    const float* __restrict__ sWi, const float* __restrict__ sbi,
    const float* __restrict__ sWo, const float* __restrict__ sbo,
    const float* __restrict__ cWi, const float* __restrict__ cbi,
    const float* __restrict__ cWo, const float* __restrict__ cbo,
    unsigned short* __restrict__ WT, float* __restrict__ BF)
{
    int s = blockIdx.y;
    int i0 = blockIdx.x * 4;
    int tid = threadIdx.x;
    const float *Wo, *Wv, *bv, *bo;
    if (s == 0) { Wo = sWo; Wv = sWi + 512 * 256; bv = sbi + 512; bo = sbo; }
    else {
        int n = s - 1;
        Wo = cWo + n * 65536;
        Wv = cWi + n * 768 * 256 + 512 * 256;
        bv = cbi + n * 768 + 512;
        bo = cbo + n * 256;
    }
    __shared__ float wo[4 * 256];
    #pragma unroll
    for (int it = 0; it < 4; ++it) {
        int idx = tid + it * 256;
        wo[idx] = Wo[i0 * 256 + idx];
    }
    __syncthreads();
    float a0 = 0.f, a1 = 0.f, a2 = 0.f, a3 = 0.f;
    for (int k = 0; k < 256; ++k) {
        float wv = Wv[k * 256 + tid];
        a0 += wo[k] * wv;
        a1 += wo[256 + k] * wv;
        a2 += wo[512 + k] * wv;
        a3 += wo[768 + k] * wv;
    }
    // scatter into WT fragment order
    {
        unsigned short vals[4] = { f2b(a0), f2b(a1), f2b(a2), f2b(a3) };
        int kk = tid >> 5, q4k = (tid >> 3) & 3, e = tid & 7;
        #pragma unroll
        for (int r = 0; r < 4; ++r) {
            int n = i0 + r;
            int w = n >> 5, ct = (n >> 4) & 1, l16n = n & 15;
            size_t idx = (((((((size_t)s * 8 + kk) * 8 + w) * 2 + ct) * 4 + q4k) * 16 + l16n) * 8) + e;
            WT[idx] = vals[r];
        }
    }
    // bias: one wave per output row (parallel), lane l covers k=4l..4l+3
    {
        int wv_ = tid >> 6, ln = tid & 63;
        float p = 0.f;
        #pragma unroll
        for (int u = 0; u < 4; ++u) {
            int k = ln * 4 + u;
            p += wo[wv_ * 256 + k] * bv[k];
        }
        #pragma unroll
        for (int o = 32; o > 0; o >>= 1) p += __shfl_xor(p, o, 64);
        if (ln == 0) BF[s * 256 + i0 + wv_] = p + bo[i0 + wv_];
    }
}

// ---------------- K2: fused GEMM + epilogue ----------------
__device__ __forceinline__ float wred(float v) {
    #pragma unroll
    for (int o = 32; o > 0; o >>= 1) v += __shfl_xor(v, o, 64);
    return v;
}

#define ASTR 264   // shorts; 528B row stride (R6's pad; 2-way bank alias = free)

// grid 1024, block 256 (4 waves). Block: rows [b0, b0+16). Wave w: GEMM cols
// [w*64, w*64+64) (ct=0..3), epilogue rows [w*4, w*4+4), lane j = lane*4.
// LDS: 4 A/Y slots (branches 1-4) + gLDS = 34304 B -> 4 blocks/CU by LDS.
// Branch order [1,2,3,4,0]; branch 0's A comes straight from global (L2-hot),
// its Y parks into slot 0.
__global__ __launch_bounds__(256, 3) void k_main(
    const float* __restrict__ x, const unsigned short* __restrict__ WT,
    const float* __restrict__ BF,
    const float* __restrict__ cln_g, const float* __restrict__ cln_b,
    const float* __restrict__ gln_g, const float* __restrict__ gln_b,
    const float* __restrict__ gW, const float* __restrict__ gb,
    const float* __restrict__ fln_g, const float* __restrict__ fln_b,
    const int* __restrict__ midx, float* __restrict__ out)
{
    __shared__ __align__(16) unsigned short Axl[4][16 * ASTR]; // 33,792 B
    __shared__ float gLDS[16 * 8];                              // 512 B

    const int m = midx[0];
    const int b0 = blockIdx.x * 16;
    const int tid = threadIdx.x;
    const int wave = tid >> 6, lane = tid & 63;
    const int l16 = lane & 15, q4 = lane >> 4;
    const int j = lane * 4;

    // q rows (fp32, registers, for residuals): 4 rows per wave
    float qv[4][4];
    #pragma unroll
    for (int rr = 0; rr < 4; ++rr) {
        int r = wave * 4 + rr;
        float4 u = *(const float4*)(x + ((size_t)(b0 + r) * 5 + m) * 256 + j);
        qv[rr][0] = u.x; qv[rr][1] = u.y; qv[rr][2] = u.z; qv[rr][3] = u.w;
    }
    float4 glg = *(const float4*)(gln_g + j);
    float4 glb = *(const float4*)(gln_b + j);

    // ---- stage tiles for branches 1..4 (slot p <-> branch p+1 <-> modal p<m?p:p+1)
    //      issue all 16 float4, compute gates under the latency, then write ----
    float4 sreg[4][4];
    #pragma unroll
    for (int p = 0; p < 4; ++p) {
        int mod = (p < m) ? p : p + 1;
        #pragma unroll
        for (int it = 0; it < 4; ++it) {
            int c = tid + it * 256;             // 16 rows x 64 float4
            sreg[p][it] = *(const float4*)(x + ((size_t)(b0 + (c >> 6)) * 5 + mod) * 256 + ((c & 63) << 2));
        }
    }

    // ---- gates (R6 pattern: full-wave wred, result to gLDS; gW from global/L2) ----
    #pragma unroll
    for (int rr = 0; rr < 4; ++rr) {
        int r = wave * 4 + rr;
        float s1 = wred(qv[rr][0] + qv[rr][1] + qv[rr][2] + qv[rr][3]);
        float s2 = wred(qv[rr][0]*qv[rr][0] + qv[rr][1]*qv[rr][1] +
                        qv[rr][2]*qv[rr][2] + qv[rr][3]*qv[rr][3]);
        float mn = s1 * (1.f / 256.f);
        float vr = s2 * (1.f / 256.f) - mn * mn;
        float rs = rsqrtf(vr + 1e-5f);
        float qln[4];
        qln[0] = (qv[rr][0] - mn) * rs * glg.x + glb.x;
        qln[1] = (qv[rr][1] - mn) * rs * glg.y + glb.y;
        qln[2] = (qv[rr][2] - mn) * rs * glg.z + glb.z;
        qln[3] = (qv[rr][3] - mn) * rs * glg.w + glb.w;
        float g[5];
        #pragma unroll
        for (int n = 0; n < 5; ++n) {
            float4 w4 = *(const float4*)(gW + n * 256 + j);
            float p = qln[0] * w4.x + qln[1] * w4.y + qln[2] * w4.z + qln[3] * w4.w;
            g[n] = wred(p) + gb[n];
        }
        float mx = g[0];
        #pragma unroll
        for (int n = 1; n < 5; ++n) mx = fmaxf(mx, g[n]);
        float es = 0.f;
        #pragma unroll
        for (int n = 0; n < 5; ++n) { g[n] = __expf(g[n] - mx); es += g[n]; }
        float inv = 1.f / es;
        if (lane == 0) {
            #pragma unroll
            for (int n = 0; n < 5; ++n) gLDS[r * 8 + n] = g[n] * inv;
        }
    }

    // ---- write the 4 staged tiles to LDS (bf16, padded rows) ----
    #pragma unroll
    for (int p = 0; p < 4; ++p) {
        #pragma unroll
        for (int it = 0; it < 4; ++it) {
            int c = tid + it * 256;
            int row = c >> 6;
            int c4 = (c & 63) << 2;
            float4 v = sreg[p][it];
            uint2 pk;
            pk.x = (unsigned int)f2b(v.x) | ((unsigned int)f2b(v.y) << 16);
            pk.y = (unsigned int)f2b(v.z) | ((unsigned int)f2b(v.w) << 16);
            *(uint2*)(&Axl[p][row * ASTR + c4]) = pk;
        }
    }
    __syncthreads();  // tiles + gLDS ready; only branch-0 A reads global from here

    float comb[4][4];
    #pragma unroll
    for (int rr = 0; rr < 4; ++rr)
        #pragma unroll
        for (int i = 0; i < 4; ++i) comb[rr][i] = 0.f;

    // ---- phases: branches [1,2,3,4,0]; branch 0 last, parks into slot 0 ----
    #pragma unroll
    for (int p = 0; p < 5; ++p) {
        const int s = (p < 4) ? (p + 1) : 0;   // branch id
        const int slot = (p < 4) ? p : 0;      // park slot
        float4 bfv = *(const float4*)(BF + s * 256 + j);
        float4 cg, cb;
        if (s > 0) {
            cg = *(const float4*)(cln_g + (s - 1) * 256 + j);
            cb = *(const float4*)(cln_b + (s - 1) * 256 + j);
        }

        // GEMM: 16x256 = A(16x256) @ WF_s^T ; wave covers 64 cols (ct=0..3).
        floatx4 acc[4];
        #pragma unroll
        for (int ct = 0; ct < 4; ++ct) acc[ct] = (floatx4){0.f, 0.f, 0.f, 0.f};
        const unsigned short* wT = WT + (size_t)s * 65536;
        #pragma unroll
        for (int h = 0; h < 8; ++h) {
            short8 bb[4];
            #pragma unroll
            for (int ct = 0; ct < 4; ++ct) {
                int wp = wave * 2 + (ct >> 1), ctp = ct & 1;
                bb[ct] = *(const short8*)(
                    wT + (((((size_t)h * 8 + wp) * 2 + ctp) * 4 + q4) * 16 + l16) * 8);
            }
            int k = h * 32 + q4 * 8;
            short8 a;
            if (p < 4) {
                a = *(const short8*)(&Axl[slot][l16 * ASTR + k]);
            } else {
                // branch 0: A-fragments straight from global (modal m, L1/L2-hot)
                const float* ap = x + ((size_t)(b0 + l16) * 5 + m) * 256 + k;
                float4 a0 = *(const float4*)(ap);
                float4 a1 = *(const float4*)(ap + 4);
                a[0] = (short)f2b(a0.x); a[1] = (short)f2b(a0.y);
                a[2] = (short)f2b(a0.z); a[3] = (short)f2b(a0.w);
                a[4] = (short)f2b(a1.x); a[5] = (short)f2b(a1.y);
                a[6] = (short)f2b(a1.z); a[7] = (short)f2b(a1.w);
            }
            #pragma unroll
            for (int ct = 0; ct < 4; ++ct)
                acc[ct] = __builtin_amdgcn_mfma_f32_16x16x32_bf16(a, bb[ct], acc[ct], 0, 0, 0);
        }
        __syncthreads();  // B_a: all waves done reading Axl[slot] / done prior epilogues

        // park Y in place over Axl[slot] (MFMA C-layout -> row-major)
        // (for p==4 slot 0's Y(branch1) was consumed 4 phases ago; ordered by B_a)
        #pragma unroll
        for (int i = 0; i < 4; ++i) {
            int r = q4 * 4 + i;
            #pragma unroll
            for (int ct = 0; ct < 4; ++ct)
                Axl[slot][r * ASTR + wave * 64 + ct * 16 + l16] = f2b(acc[ct][i]);
        }
        __syncthreads();  // B1: park visible

        // epilogue partial: comb += g_s * (s==0 ? y : LN(q+y))
        if (s == 0) {
            #pragma unroll
            for (int rr = 0; rr < 4; ++rr) {
                int r = wave * 4 + rr;
                uint2 u = *(const uint2*)(&Axl[slot][r * ASTR + j]);
                float y0 = b2f(u.x & 0xffff) + bfv.x, y1 = b2f(u.x >> 16) + bfv.y;
                float y2 = b2f(u.y & 0xffff) + bfv.z, y3 = b2f(u.y >> 16) + bfv.w;
                float g0 = gLDS[r * 8 + 0];
                comb[rr][0] += g0 * y0; comb[rr][1] += g0 * y1;
                comb[rr][2] += g0 * y2; comb[rr][3] += g0 * y3;
            }
        } else {
            #pragma unroll
            for (int rr = 0; rr < 4; ++rr) {
                int r = wave * 4 + rr;
                uint2 u = *(const uint2*)(&Axl[slot][r * ASTR + j]);
                float t0 = qv[rr][0] + b2f(u.x & 0xffff) + bfv.x;
                float t1 = qv[rr][1] + b2f(u.x >> 16)    + bfv.y;
                float t2 = qv[rr][2] + b2f(u.y & 0xffff) + bfv.z;
                float t3 = qv[rr][3] + b2f(u.y >> 16)    + bfv.w;
                float s1 = wred(t0 + t1 + t2 + t3);
                float s2 = wred(t0*t0 + t1*t1 + t2*t2 + t3*t3);
                float mn = s1 * (1.f / 256.f);
                float vr = s2 * (1.f / 256.f) - mn * mn;
                float rs = rsqrtf(vr + 1e-5f);
                float gs = gLDS[r * 8 + s];
                comb[rr][0] += gs * ((t0 - mn) * rs * cg.x + cb.x);
                comb[rr][1] += gs * ((t1 - mn) * rs * cg.y + cb.y);
                comb[rr][2] += gs * ((t2 - mn) * rs * cg.z + cb.z);
                comb[rr][3] += gs * ((t3 - mn) * rs * cg.w + cb.w);
            }
        }
        // no barrier at loop end: phases 0-3 read only the NEXT untouched slot;
        // phase 4 reads global. Epilogue reads of this slot are ordered before
        // any later write to it by the next phases' B_a barriers.
    }

    // final LN and store (float4-coalesced)
    float4 fg = *(const float4*)(fln_g + j);
    float4 fb = *(const float4*)(fln_b + j);
    #pragma unroll
    for (int rr = 0; rr < 4; ++rr) {
        int r = wave * 4 + rr;
        float t0 = qv[rr][0] + comb[rr][0], t1 = qv[rr][1] + comb[rr][1];
        float t2 = qv[rr][2] + comb[rr][2], t3 = qv[rr][3] + comb[rr][3];
        float s1 = wred(t0 + t1 + t2 + t3);
        float s2 = wred(t0*t0 + t1*t1 + t2*t2 + t3*t3);
        float mn = s1 * (1.f / 256.f);
        float vr = s2 * (1.f / 256.f) - mn * mn;
        float rs = rsqrtf(vr + 1e-5f);
        float4 ov;
        ov.x = (t0 - mn) * rs * fg.x + fb.x;
        ov.y = (t1 - mn) * rs * fg.y + fb.y;
        ov.z = (t2 - mn) * rs * fg.z + fb.z;
        ov.w = (t3 - mn) * rs * fg.w + fb.w;
        *(float4*)(out + (size_t)(b0 + r) * 256 + j) = ov;
    }
}

extern "C" void kernel_launch(void* const* d_in, const int* in_sizes, int n_in,
                              void* d_out, int out_size, void* d_ws, size_t ws_size,
                              hipStream_t stream) {
    const float* x    = (const float*)d_in[0];
    const float* sWi  = (const float*)d_in[1];
    const float* sbi  = (const float*)d_in[2];
    const float* sWo  = (const float*)d_in[3];
    const float* sbo  = (const float*)d_in[4];
    const float* cWi  = (const float*)d_in[5];
    const float* cbi  = (const float*)d_in[6];
    const float* cWo  = (const float*)d_in[7];
    const float* cbo  = (const float*)d_in[8];
    const float* clng = (const float*)d_in[9];
    const float* clnb = (const float*)d_in[10];
    const float* glng = (const float*)d_in[11];
    const float* glnb = (const float*)d_in[12];
    const float* gW   = (const float*)d_in[13];
    const float* gb   = (const float*)d_in[14];
    const float* flng = (const float*)d_in[15];
    const float* flnb = (const float*)d_in[16];
    const int* midx   = (const int*)d_in[17];
    float* out        = (float*)d_out;

    char* ws = (char*)d_ws;
    unsigned short* WT = (unsigned short*)ws;         // 5*256*256*2 = 655360 B (fragment order)
    float* BF          = (float*)(ws + 655360);       // 5*256*4 = 5120 B  (total 660480 B)

    k_fuse<<<dim3(64, 5), 256, 0, stream>>>(sWi, sbi, sWo, sbo, cWi, cbi, cWo, cbo, WT, BF);
    k_main<<<1024, 256, 0, stream>>>(x, WT, BF, clng, clnb, glng, glnb, gW, gb, flng, flnb, midx, out);
}